// Round 3
// baseline (2750.800 us; speedup 1.0000x reference)
//
#include <hip/hip_runtime.h>

typedef unsigned long long u64;

#define THR 0.5f

// Convert one cxcywh box to ltrb + area, with FP contraction OFF so every op
// matches numpy's rn-per-op semantics bit-exactly (needed for the NMS >= 0.5
// predicate; a fused cx - 0.5*w -> fma differs in the last ulp).
__device__ __forceinline__ void conv_box(const float4 b, float& l, float& t,
                                         float& r, float& bo, float& a) {
  #pragma clang fp contract(off)
  float hw = 0.5f * b.z;
  float hh = 0.5f * b.w;
  l = b.x - hw;
  t = b.y - hh;
  r = b.x + hw;
  bo = b.y + hh;
  a = (r - l) * (bo - t);
}

__global__ void k_zero(int* __restrict__ rank, int n) {
  int i = blockIdx.x * blockDim.x + threadIdx.x;
  if (i < n) rank[i] = 0;
}

// Stable descending rank == stable argsort(-scores) position.
__global__ void k_rank(const float* __restrict__ scores, int* __restrict__ rank,
                       int n, int jchunk) {
  int i = blockIdx.x * blockDim.x + threadIdx.x;
  if (i >= n) return;
  float si = scores[i];
  int j0 = blockIdx.y * jchunk;
  int j1 = min(j0 + jchunk, n);
  int c = 0;
  for (int j = j0; j < j1; ++j) {
    float sj = scores[j];
    c += ((sj > si) || (sj == si && j < i)) ? 1 : 0;
  }
  if (c) atomicAdd(rank + i, c);
}

__global__ void k_scatter(const float4* __restrict__ boxes, const int* __restrict__ rank,
                          float* __restrict__ sl, float* __restrict__ st,
                          float* __restrict__ sr, float* __restrict__ sb,
                          float* __restrict__ sa, int* __restrict__ sidx, int n) {
  int i = blockIdx.x * blockDim.x + threadIdx.x;
  if (i >= n) return;
  float l, t, r, b, a;
  conv_box(boxes[i], l, t, r, b, a);
  int k = rank[i];
  sl[k] = l; st[k] = t; sr[k] = r; sb[k] = b; sa[k] = a; sidx[k] = i;
}

// mask[k][w] bit b (j = w*64+b) set iff j>k, j<n, iou_nms(k,j) >= 0.5.
// Reference does NOT clamp the intersection on the NMS path — replicate
// exactly (contraction off, strict IEEE f32 division, same op order).
__global__ void k_mask(const float* __restrict__ sl, const float* __restrict__ st,
                       const float* __restrict__ sr, const float* __restrict__ sb,
                       const float* __restrict__ sa,
                       u64* __restrict__ mask, u64* __restrict__ diag,
                       int n, int wstride) {
  #pragma clang fp contract(off)
  int k = blockIdx.x * blockDim.x + threadIdx.x;
  if (k >= n) return;
  int w = blockIdx.y;
  int jbase = w << 6;
  u64 word = 0;
  if (jbase + 63 > k) {
    float l = sl[k], t = st[k], r = sr[k], b = sb[k], a = sa[k];
    int jend = min(jbase + 64, n);
    for (int j = max(jbase, k + 1); j < jend; ++j) {
      float lmax = fmaxf(l, sl[j]);
      float tmax = fmaxf(t, st[j]);
      float rmin = fminf(r, sr[j]);
      float bmin = fminf(b, sb[j]);
      float wd = rmin - lmax;
      float hd = bmin - tmax;
      float inter = wd * hd;               // no clamp (matches reference NMS path)
      float denom = (a + sa[j]) - inter;
      float q = inter / denom;             // IEEE f32 div
      if (q >= THR) word |= 1ull << (j - jbase);
    }
  }
  mask[(size_t)k * wstride + w] = word;
  if ((k >> 6) == w) diag[k] = word;
}

// ---------------------------------------------------------------------------
// Greedy serial NMS scan — 4 waves (256 threads), latency-engineered:
//  * suppression state in REGISTERS (r0/r1/r2 per lane: words lane,+64,+128)
//  * the one word group g+1 needs is published via double-buffered bcast[2][4]
//  * fold = branchless masked OR over all 64 rows (independent, pipelineable
//    loads — round-2 bug: dynamic while(kept) loop serialized ~2500 x 500cy
//    global round-trips), rows split 16/wave, future-words only (w > g)
//  * next group's diag/sidx prefetched into registers at top of group
//  * chunk-skip (all-8-suppressed) makes late groups nearly free
// ---------------------------------------------------------------------------
__device__ __forceinline__ void scan_body4(
    const u64* __restrict__ mask, const u64* __restrict__ diag,
    const int* __restrict__ sidx, float* __restrict__ keep,
    int n, int wstride, u64 (*dsh4)[64], u64 (*bcast)[4]) {
  int t = threadIdx.x, wv = t >> 6, lane = t & 63;
  int ng = (n + 63) >> 6;
  int w1 = lane + 64, w2 = lane + 128;
  u64 r0 = 0, r1 = 0, r2 = 0;
  if (t < 4) bcast[0][t] = 0;
  dsh4[wv][lane] = diag[lane];           // each wave keeps a private diag copy
  int scur = 0;
  if (wv == 0 && lane < n) scur = sidx[lane];
  __syncthreads();
  for (int g = 0; g < ng; ++g) {
    int base = g << 6;
    u64 s = bcast[g & 1][0] | bcast[g & 1][1] | bcast[g & 1][2] | bcast[g & 1][3];
    // prefetch next group's diag/sidx (latency hides under chain+fold)
    int nxt = base + 64 + lane;
    u64 dnext = (g + 1 < ng) ? diag[nxt] : 0;
    int snew = (wv == 0 && nxt < n) ? sidx[nxt] : 0;
    int valid = n - base;
    if (valid < 64) s |= (~0ull) << valid;   // nonexistent boxes = suppressed
    u64 kw = 0;
    const u64* dsh = dsh4[wv];
    #pragma unroll
    for (int c = 0; c < 8; ++c) {
      int b0 = c << 3;
      if ((unsigned)((s >> b0) & 0xFFull) != 0xFFu) {   // skip fully-suppressed byte
        u64 e0 = dsh[b0 + 0], e1 = dsh[b0 + 1], e2 = dsh[b0 + 2], e3 = dsh[b0 + 3];
        u64 e4 = dsh[b0 + 4], e5 = dsh[b0 + 5], e6 = dsh[b0 + 6], e7 = dsh[b0 + 7];
        #define STEP(Q, EQ) if (!((s >> (b0 + Q)) & 1ull)) { kw |= 1ull << (b0 + Q); s |= EQ; }
        STEP(0, e0) STEP(1, e1) STEP(2, e2) STEP(3, e3)
        STEP(4, e4) STEP(5, e5) STEP(6, e6) STEP(7, e7)
        #undef STEP
      }
    }
    if (wv == 0 && base + lane < n)
      keep[scur] = ((kw >> lane) & 1ull) ? 1.0f : 0.0f;
    // fold: wave wv owns rows 16*wv..16*wv+15; branchless masked OR so all
    // loads are independent and pipeline (BW-bound, not latency-bound)
    if ((kw >> (wv << 4)) & 0xFFFFull) {
      u64 a0 = 0, a1 = 0, a2 = 0;
      #pragma unroll 4
      for (int q = 0; q < 16; ++q) {
        int b = (wv << 4) + q;
        u64 m = (u64)0 - ((kw >> b) & 1ull);
        const u64* row = mask + (size_t)(base + b) * wstride;
        if (lane > g)            a0 |= row[lane] & m;
        if (w1 > g && w1 < ng)   a1 |= row[w1] & m;
        if (w2 > g && w2 < ng)   a2 |= row[w2] & m;
      }
      r0 |= a0; r1 |= a1; r2 |= a2;
    }
    // publish the single word group g+1 will need
    int wn = g + 1;
    if (wn < ng) {
      int slot = wn >> 6;
      u64 v = (slot == 0) ? r0 : (slot == 1) ? r1 : r2;
      if (lane == (wn & 63)) bcast[wn & 1][wv] = v;
    }
    dsh4[wv][lane] = dnext;
    scur = snew;
    __syncthreads();
  }
}

__global__ __launch_bounds__(256, 1) void k_scan2(const u64* __restrict__ mask,
                                                  const u64* __restrict__ diag,
                                                  const int* __restrict__ sidx,
                                                  float* __restrict__ keep,
                                                  int n, int wstride) {
  __shared__ u64 dsh4[4][64];
  __shared__ u64 bcast[2][4];
  scan_body4(mask, diag, sidx, keep, n, wstride, dsh4, bcast);
}

// Pairwise IoU, original order, WITH clamp. Loose 2e-2 threshold -> fast rcp.
__device__ __forceinline__ float iou_one(float li, float ti, float ri, float bi, float ai,
                                         float lj, float tj, float rj, float bj, float aj) {
  float lmax = fmaxf(li, lj);
  float tmax = fmaxf(ti, tj);
  float rmin = fminf(ri, rj);
  float bmin = fminf(bi, bj);
  float w = fmaxf(rmin - lmax, 0.0f);
  float h = fmaxf(bmin - tmax, 0.0f);
  float inter = w * h;
  float denom = (ai + aj) - inter;
  return inter * __builtin_amdgcn_rcpf(denom);
}

__device__ __forceinline__ void iou_body(const float4* __restrict__ boxes,
                                         float* __restrict__ out,
                                         int n, int rpb, int bx, int by) {
  int nj4 = (n + 3) >> 2;
  int j4 = bx * 256 + threadIdx.x;
  if (j4 >= nj4) return;
  int j = j4 << 2;
  int jc1 = min(j + 1, n - 1), jc2 = min(j + 2, n - 1), jc3 = min(j + 3, n - 1);
  float l0,t0,r0,b0,a0, l1,t1,r1,b1,a1, l2,t2,r2,b2,a2, l3,t3,r3,b3,a3;
  conv_box(boxes[j],   l0,t0,r0,b0,a0);
  conv_box(boxes[jc1], l1,t1,r1,b1,a1);
  conv_box(boxes[jc2], l2,t2,r2,b2,a2);
  conv_box(boxes[jc3], l3,t3,r3,b3,a3);
  bool full = (j + 3) < n;
  for (int rr = 0; rr < rpb; ++rr) {
    int i = by * rpb + rr;
    if (i >= n) return;
    float li,ti,ri,bi,ai;
    conv_box(boxes[i], li,ti,ri,bi,ai);
    float4 o;
    o.x = iou_one(li,ti,ri,bi,ai, l0,t0,r0,b0,a0);
    o.y = iou_one(li,ti,ri,bi,ai, l1,t1,r1,b1,a1);
    o.z = iou_one(li,ti,ri,bi,ai, l2,t2,r2,b2,a2);
    o.w = iou_one(li,ti,ri,bi,ai, l3,t3,r3,b3,a3);
    size_t row = (size_t)i * n;
    if (full) {
      *reinterpret_cast<float4*>(out + row + j) = o;
    } else {
      out[row + j] = o.x;
      if (j + 1 < n) out[row + j + 1] = o.y;
      if (j + 2 < n) out[row + j + 2] = o.z;
    }
  }
}

__global__ void k_iou(const float4* __restrict__ boxes, float* __restrict__ out,
                      int n, int rpb) {
  iou_body(boxes, out, n, rpb, blockIdx.x, blockIdx.y);
}

// Fused: block 0 runs the 4-wave NMS scan from d_ws while all other blocks
// stream the 400MB IoU matrix — scan latency hides under the write-bound IoU.
// No hazard: scan reads ws + writes keep (=out+NN); iou writes out[0,NN).
__global__ __launch_bounds__(256) void k_fused(const float4* __restrict__ boxes,
                                               float* __restrict__ out,
                                               const u64* __restrict__ mask,
                                               const u64* __restrict__ diag,
                                               const int* __restrict__ sidx,
                                               float* __restrict__ keep,
                                               int n, int wstride, int rpb, int gx) {
  __shared__ u64 dsh4[4][64];
  __shared__ u64 bcast[2][4];
  if (blockIdx.x == 0) {
    scan_body4(mask, diag, sidx, keep, n, wstride, dsh4, bcast);
    return;
  }
  int id = blockIdx.x - 1;
  iou_body(boxes, out, n, rpb, id % gx, id / gx);
}

extern "C" void kernel_launch(void* const* d_in, const int* in_sizes, int n_in,
                              void* d_out, int out_size, void* d_ws, size_t ws_size,
                              hipStream_t stream) {
  const float* boxes = (const float*)d_in[0];
  const float* scores = (const float*)d_in[1];
  int n = in_sizes[1];
  float* out = (float*)d_out;
  size_t NN = (size_t)n * (size_t)n;
  float* keep = out + NN;

  int words = (n + 63) >> 6;
  int wstride = (words + 3) & ~3;
  size_t need = (size_t)n * wstride * 8          // mask
              + (size_t)words * 64 * 8           // diag
              + 256                              // align slack
              + (size_t)n * 4 * 7;               // sl,st,sr,sb,sa,sidx,rank
  bool use_ws = (ws_size >= need);

  char* base = use_ws ? (char*)d_ws : (char*)d_out;
  size_t off = 0;
  u64* mask = (u64*)(base + off); off += (size_t)n * wstride * 8;
  u64* diag = (u64*)(base + off); off += (size_t)words * 64 * 8;
  off = (off + 255) & ~(size_t)255;
  float* sl  = (float*)(base + off); off += (size_t)n * 4;
  float* st_ = (float*)(base + off); off += (size_t)n * 4;
  float* sr  = (float*)(base + off); off += (size_t)n * 4;
  float* sb  = (float*)(base + off); off += (size_t)n * 4;
  float* sa  = (float*)(base + off); off += (size_t)n * 4;
  int* sidx  = (int*)(base + off); off += (size_t)n * 4;
  int* rank  = (int*)(base + off); off += (size_t)n * 4;

  int nb = (n + 255) / 256;
  k_zero<<<nb, 256, 0, stream>>>(rank, n);

  int jblocks = 40;
  int jchunk = (n + jblocks - 1) / jblocks;
  k_rank<<<dim3(nb, jblocks), 256, 0, stream>>>(scores, rank, n, jchunk);

  k_scatter<<<nb, 256, 0, stream>>>((const float4*)boxes, rank, sl, st_, sr, sb, sa, sidx, n);

  k_mask<<<dim3(nb, words), 256, 0, stream>>>(sl, st_, sr, sb, sa, mask, diag, n, wstride);

  int rpb = 10;
  int nj4 = (n + 3) >> 2;
  int gx = (nj4 + 255) / 256;
  int gy = (n + rpb - 1) / rpb;

  if (use_ws) {
    k_fused<<<gx * gy + 1, 256, 0, stream>>>((const float4*)boxes, out, mask, diag,
                                             sidx, keep, n, wstride, rpb, gx);
  } else {
    // scratch lives in front of out: must finish scan before iou overwrites it
    k_scan2<<<1, 256, 0, stream>>>(mask, diag, sidx, keep, n, wstride);
    k_iou<<<dim3(gx, gy), 256, 0, stream>>>((const float4*)boxes, out, n, rpb);
  }
}

// Round 4
// 523.760 us; speedup vs baseline: 5.2520x; 5.2520x over previous
//
#include <hip/hip_runtime.h>

typedef unsigned long long u64;

#define THR 0.5f

// Convert one cxcywh box to ltrb + area, with FP contraction OFF so every op
// matches numpy's rn-per-op semantics bit-exactly (needed for the NMS >= 0.5
// predicate; a fused cx - 0.5*w -> fma differs in the last ulp).
__device__ __forceinline__ void conv_box(const float4 b, float& l, float& t,
                                         float& r, float& bo, float& a) {
  #pragma clang fp contract(off)
  float hw = 0.5f * b.z;
  float hh = 0.5f * b.w;
  l = b.x - hw;
  t = b.y - hh;
  r = b.x + hw;
  bo = b.y + hh;
  a = (r - l) * (bo - t);
}

__global__ void k_zero(int* __restrict__ rank, int n) {
  int i = blockIdx.x * blockDim.x + threadIdx.x;
  if (i < n) rank[i] = 0;
}

// Stable descending rank == stable argsort(-scores) position.
__global__ void k_rank(const float* __restrict__ scores, int* __restrict__ rank,
                       int n, int jchunk) {
  int i = blockIdx.x * blockDim.x + threadIdx.x;
  if (i >= n) return;
  float si = scores[i];
  int j0 = blockIdx.y * jchunk;
  int j1 = min(j0 + jchunk, n);
  int c = 0;
  for (int j = j0; j < j1; ++j) {
    float sj = scores[j];
    c += ((sj > si) || (sj == si && j < i)) ? 1 : 0;
  }
  if (c) atomicAdd(rank + i, c);
}

__global__ void k_scatter(const float4* __restrict__ boxes, const int* __restrict__ rank,
                          float* __restrict__ sl, float* __restrict__ st,
                          float* __restrict__ sr, float* __restrict__ sb,
                          float* __restrict__ sa, int* __restrict__ sidx, int n) {
  int i = blockIdx.x * blockDim.x + threadIdx.x;
  if (i >= n) return;
  float l, t, r, b, a;
  conv_box(boxes[i], l, t, r, b, a);
  int k = rank[i];
  sl[k] = l; st[k] = t; sr[k] = r; sb[k] = b; sa[k] = a; sidx[k] = i;
}

// mask[k][w] bit b (j = w*64+b) set iff j>k, j<n, iou_nms(k,j) >= 0.5.
// Reference does NOT clamp the intersection on the NMS path — replicate
// exactly (contraction off, strict IEEE f32 division, same op order).
__global__ void k_mask(const float* __restrict__ sl, const float* __restrict__ st,
                       const float* __restrict__ sr, const float* __restrict__ sb,
                       const float* __restrict__ sa,
                       u64* __restrict__ mask, u64* __restrict__ diag,
                       int n, int wstride) {
  #pragma clang fp contract(off)
  int k = blockIdx.x * blockDim.x + threadIdx.x;
  if (k >= n) return;
  int w = blockIdx.y;
  int jbase = w << 6;
  u64 word = 0;
  if (jbase + 63 > k) {
    float l = sl[k], t = st[k], r = sr[k], b = sb[k], a = sa[k];
    int jend = min(jbase + 64, n);
    for (int j = max(jbase, k + 1); j < jend; ++j) {
      float lmax = fmaxf(l, sl[j]);
      float tmax = fmaxf(t, st[j]);
      float rmin = fminf(r, sr[j]);
      float bmin = fminf(b, sb[j]);
      float wd = rmin - lmax;
      float hd = bmin - tmax;
      float inter = wd * hd;               // no clamp (matches reference NMS path)
      float denom = (a + sa[j]) - inter;
      float q = inter / denom;             // IEEE f32 div
      if (q >= THR) word |= 1ull << (j - jbase);
    }
  }
  mask[(size_t)k * wstride + w] = word;
  if ((k >> 6) == w) diag[k] = word;
}

// ---------------------------------------------------------------------------
// Greedy serial NMS scan — 256 threads.
//  Phase A (wave 0 only): serial 64-bit chain over the diagonal block (LDS),
//    diag/sidx for g+1 prefetched at top so latency hides under the chain;
//    kept bits compacted into LDS kept[] (padded to x8 with row 0).
//  Phase B (all threads): thread t owns word t of rem[] (LDS). Fold = for
//    each batch of 8 kept rows, 8 UNCONDITIONAL coalesced loads row[t]
//    (consecutive t -> contiguous 1.25KB per row), one waitcnt, 8 masked ORs.
//    Round-3 bug: 48 per-lane predicated loads serialized at ~800cy each
//    (41k cy/group). Now ~2 batches -> ~2 latencies per group.
// ---------------------------------------------------------------------------
__device__ __forceinline__ void scan_body5(
    const u64* __restrict__ mask, const u64* __restrict__ diag,
    const int* __restrict__ sidx, float* __restrict__ keep,
    int n, int wstride, u64* rem, u64* dsh, int* kept, int* nk_sh) {
  int t = threadIdx.x, wv = t >> 6, lane = t & 63;
  int ng = (n + 63) >> 6;
  rem[t] = 0;
  int scur = 0;
  if (wv == 0) {
    dsh[lane] = diag[lane];
    if (lane < n) scur = sidx[lane];
  }
  __syncthreads();
  for (int g = 0; g < ng; ++g) {
    int base = g << 6;
    if (wv == 0) {
      // prefetch next group's diag/sidx (latency hides under the chain)
      int nxt = base + 64 + lane;
      u64 dnext = (g + 1 < ng) ? diag[nxt] : 0;
      int snew = (g + 1 < ng && nxt < n) ? sidx[nxt] : 0;
      u64 s = rem[g];
      int valid = n - base;
      if (valid < 64) s |= (~0ull) << valid;   // nonexistent boxes = suppressed
      u64 kw = 0;
      #pragma unroll
      for (int c = 0; c < 8; ++c) {
        int b0 = c << 3;
        if ((unsigned)((s >> b0) & 0xFFull) != 0xFFu) {  // skip suppressed byte
          u64 e0 = dsh[b0 + 0], e1 = dsh[b0 + 1], e2 = dsh[b0 + 2], e3 = dsh[b0 + 3];
          u64 e4 = dsh[b0 + 4], e5 = dsh[b0 + 5], e6 = dsh[b0 + 6], e7 = dsh[b0 + 7];
          #define STEP(Q, EQ) if (!((s >> (b0 + Q)) & 1ull)) { kw |= 1ull << (b0 + Q); s |= EQ; }
          STEP(0, e0) STEP(1, e1) STEP(2, e2) STEP(3, e3)
          STEP(4, e4) STEP(5, e5) STEP(6, e6) STEP(7, e7)
          #undef STEP
        }
      }
      if (base + lane < n)
        keep[scur] = ((kw >> lane) & 1ull) ? 1.0f : 0.0f;
      // compact kept bits -> LDS list, pad to x8 with row 0 (discarded by i<nk)
      int nk = __popcll(kw);
      if ((kw >> lane) & 1ull) {
        int pos = __popcll(kw & ((1ull << lane) - 1ull));
        kept[pos] = lane;
      }
      int npad = (nk + 7) & ~7;
      if (lane >= nk && lane < npad) kept[lane] = 0;
      if (lane == 0) *nk_sh = nk;
      dsh[lane] = dnext;   // after all chain reads (wave-ordered LDS)
      scur = snew;
    }
    __syncthreads();
    int nk = *nk_sh;
    if (t < ng && nk) {
      u64 acc = 0;
      for (int i = 0; i < nk; i += 8) {
        const u64* r0 = mask + (size_t)(base + kept[i + 0]) * wstride;
        const u64* r1 = mask + (size_t)(base + kept[i + 1]) * wstride;
        const u64* r2 = mask + (size_t)(base + kept[i + 2]) * wstride;
        const u64* r3 = mask + (size_t)(base + kept[i + 3]) * wstride;
        const u64* r4 = mask + (size_t)(base + kept[i + 4]) * wstride;
        const u64* r5 = mask + (size_t)(base + kept[i + 5]) * wstride;
        const u64* r6 = mask + (size_t)(base + kept[i + 6]) * wstride;
        const u64* r7 = mask + (size_t)(base + kept[i + 7]) * wstride;
        u64 v0 = r0[t], v1 = r1[t], v2 = r2[t], v3 = r3[t];
        u64 v4 = r4[t], v5 = r5[t], v6 = r6[t], v7 = r7[t];
        acc |= v0;
        if (i + 1 < nk) acc |= v1;
        if (i + 2 < nk) acc |= v2;
        if (i + 3 < nk) acc |= v3;
        if (i + 4 < nk) acc |= v4;
        if (i + 5 < nk) acc |= v5;
        if (i + 6 < nk) acc |= v6;
        if (i + 7 < nk) acc |= v7;
      }
      rem[t] |= acc;
    }
    __syncthreads();
  }
}

__global__ __launch_bounds__(256, 1) void k_scan2(const u64* __restrict__ mask,
                                                  const u64* __restrict__ diag,
                                                  const int* __restrict__ sidx,
                                                  float* __restrict__ keep,
                                                  int n, int wstride) {
  __shared__ u64 rem[256];
  __shared__ u64 dsh[64];
  __shared__ int kept[64];
  __shared__ int nk_sh;
  scan_body5(mask, diag, sidx, keep, n, wstride, rem, dsh, kept, &nk_sh);
}

// Pairwise IoU, original order, WITH clamp. Loose 2e-2 threshold -> fast rcp.
__device__ __forceinline__ float iou_one(float li, float ti, float ri, float bi, float ai,
                                         float lj, float tj, float rj, float bj, float aj) {
  float lmax = fmaxf(li, lj);
  float tmax = fmaxf(ti, tj);
  float rmin = fminf(ri, rj);
  float bmin = fminf(bi, bj);
  float w = fmaxf(rmin - lmax, 0.0f);
  float h = fmaxf(bmin - tmax, 0.0f);
  float inter = w * h;
  float denom = (ai + aj) - inter;
  return inter * __builtin_amdgcn_rcpf(denom);
}

__device__ __forceinline__ void iou_body(const float4* __restrict__ boxes,
                                         float* __restrict__ out,
                                         int n, int rpb, int bx, int by) {
  int nj4 = (n + 3) >> 2;
  int j4 = bx * 256 + threadIdx.x;
  if (j4 >= nj4) return;
  int j = j4 << 2;
  int jc1 = min(j + 1, n - 1), jc2 = min(j + 2, n - 1), jc3 = min(j + 3, n - 1);
  float l0,t0,r0,b0,a0, l1,t1,r1,b1,a1, l2,t2,r2,b2,a2, l3,t3,r3,b3,a3;
  conv_box(boxes[j],   l0,t0,r0,b0,a0);
  conv_box(boxes[jc1], l1,t1,r1,b1,a1);
  conv_box(boxes[jc2], l2,t2,r2,b2,a2);
  conv_box(boxes[jc3], l3,t3,r3,b3,a3);
  bool full = (j + 3) < n;
  for (int rr = 0; rr < rpb; ++rr) {
    int i = by * rpb + rr;
    if (i >= n) return;
    float li,ti,ri,bi,ai;
    conv_box(boxes[i], li,ti,ri,bi,ai);
    float4 o;
    o.x = iou_one(li,ti,ri,bi,ai, l0,t0,r0,b0,a0);
    o.y = iou_one(li,ti,ri,bi,ai, l1,t1,r1,b1,a1);
    o.z = iou_one(li,ti,ri,bi,ai, l2,t2,r2,b2,a2);
    o.w = iou_one(li,ti,ri,bi,ai, l3,t3,r3,b3,a3);
    size_t row = (size_t)i * n;
    if (full) {
      *reinterpret_cast<float4*>(out + row + j) = o;
    } else {
      out[row + j] = o.x;
      if (j + 1 < n) out[row + j + 1] = o.y;
      if (j + 2 < n) out[row + j + 2] = o.z;
    }
  }
}

__global__ void k_iou(const float4* __restrict__ boxes, float* __restrict__ out,
                      int n, int rpb) {
  iou_body(boxes, out, n, rpb, blockIdx.x, blockIdx.y);
}

// Fused: block 0 runs the NMS scan from d_ws while all other blocks stream
// the 400MB IoU matrix — scan latency hides under the write-bound IoU.
// No hazard: scan reads ws + writes keep (=out+NN); iou writes out[0,NN).
__global__ __launch_bounds__(256) void k_fused(const float4* __restrict__ boxes,
                                               float* __restrict__ out,
                                               const u64* __restrict__ mask,
                                               const u64* __restrict__ diag,
                                               const int* __restrict__ sidx,
                                               float* __restrict__ keep,
                                               int n, int wstride, int rpb, int gx) {
  __shared__ u64 rem[256];
  __shared__ u64 dsh[64];
  __shared__ int kept[64];
  __shared__ int nk_sh;
  if (blockIdx.x == 0) {
    scan_body5(mask, diag, sidx, keep, n, wstride, rem, dsh, kept, &nk_sh);
    return;
  }
  int id = blockIdx.x - 1;
  iou_body(boxes, out, n, rpb, id % gx, id / gx);
}

extern "C" void kernel_launch(void* const* d_in, const int* in_sizes, int n_in,
                              void* d_out, int out_size, void* d_ws, size_t ws_size,
                              hipStream_t stream) {
  const float* boxes = (const float*)d_in[0];
  const float* scores = (const float*)d_in[1];
  int n = in_sizes[1];
  float* out = (float*)d_out;
  size_t NN = (size_t)n * (size_t)n;
  float* keep = out + NN;

  int words = (n + 63) >> 6;
  int wstride = (words + 3) & ~3;
  size_t need = (size_t)n * wstride * 8          // mask
              + (size_t)words * 64 * 8           // diag
              + 256                              // align slack
              + (size_t)n * 4 * 7;               // sl,st,sr,sb,sa,sidx,rank
  bool use_ws = (ws_size >= need);

  char* base = use_ws ? (char*)d_ws : (char*)d_out;
  size_t off = 0;
  u64* mask = (u64*)(base + off); off += (size_t)n * wstride * 8;
  u64* diag = (u64*)(base + off); off += (size_t)words * 64 * 8;
  off = (off + 255) & ~(size_t)255;
  float* sl  = (float*)(base + off); off += (size_t)n * 4;
  float* st_ = (float*)(base + off); off += (size_t)n * 4;
  float* sr  = (float*)(base + off); off += (size_t)n * 4;
  float* sb  = (float*)(base + off); off += (size_t)n * 4;
  float* sa  = (float*)(base + off); off += (size_t)n * 4;
  int* sidx  = (int*)(base + off); off += (size_t)n * 4;
  int* rank  = (int*)(base + off); off += (size_t)n * 4;

  int nb = (n + 255) / 256;
  k_zero<<<nb, 256, 0, stream>>>(rank, n);

  int jblocks = 40;
  int jchunk = (n + jblocks - 1) / jblocks;
  k_rank<<<dim3(nb, jblocks), 256, 0, stream>>>(scores, rank, n, jchunk);

  k_scatter<<<nb, 256, 0, stream>>>((const float4*)boxes, rank, sl, st_, sr, sb, sa, sidx, n);

  k_mask<<<dim3(nb, words), 256, 0, stream>>>(sl, st_, sr, sb, sa, mask, diag, n, wstride);

  int rpb = 10;
  int nj4 = (n + 3) >> 2;
  int gx = (nj4 + 255) / 256;
  int gy = (n + rpb - 1) / rpb;

  if (use_ws) {
    k_fused<<<gx * gy + 1, 256, 0, stream>>>((const float4*)boxes, out, mask, diag,
                                             sidx, keep, n, wstride, rpb, gx);
  } else {
    // scratch lives in front of out: must finish scan before iou overwrites it
    k_scan2<<<1, 256, 0, stream>>>(mask, diag, sidx, keep, n, wstride);
    k_iou<<<dim3(gx, gy), 256, 0, stream>>>((const float4*)boxes, out, n, rpb);
  }
}

// Round 5
// 383.155 us; speedup vs baseline: 7.1793x; 1.3670x over previous
//
#include <hip/hip_runtime.h>

typedef unsigned long long u64;

#define THR 0.5f

// Convert one cxcywh box to ltrb + area, with FP contraction OFF so every op
// matches numpy's rn-per-op semantics bit-exactly (needed for the NMS >= 0.5
// predicate; a fused cx - 0.5*w -> fma differs in the last ulp).
__device__ __forceinline__ void conv_box(const float4 b, float& l, float& t,
                                         float& r, float& bo, float& a) {
  #pragma clang fp contract(off)
  float hw = 0.5f * b.z;
  float hh = 0.5f * b.w;
  l = b.x - hw;
  t = b.y - hh;
  r = b.x + hw;
  bo = b.y + hh;
  a = (r - l) * (bo - t);
}

__global__ void k_zero(int* __restrict__ rank, int n) {
  int i = blockIdx.x * blockDim.x + threadIdx.x;
  if (i < n) rank[i] = 0;
}

// Stable descending rank == stable argsort(-scores) position.
__global__ void k_rank(const float* __restrict__ scores, int* __restrict__ rank,
                       int n, int jchunk) {
  int i = blockIdx.x * blockDim.x + threadIdx.x;
  if (i >= n) return;
  float si = scores[i];
  int j0 = blockIdx.y * jchunk;
  int j1 = min(j0 + jchunk, n);
  int c = 0;
  for (int j = j0; j < j1; ++j) {
    float sj = scores[j];
    c += ((sj > si) || (sj == si && j < i)) ? 1 : 0;
  }
  if (c) atomicAdd(rank + i, c);
}

__global__ void k_scatter(const float4* __restrict__ boxes, const int* __restrict__ rank,
                          float* __restrict__ sl, float* __restrict__ st,
                          float* __restrict__ sr, float* __restrict__ sb,
                          float* __restrict__ sa, int* __restrict__ sidx, int n) {
  int i = blockIdx.x * blockDim.x + threadIdx.x;
  if (i >= n) return;
  float l, t, r, b, a;
  conv_box(boxes[i], l, t, r, b, a);
  int k = rank[i];
  sl[k] = l; st[k] = t; sr[k] = r; sb[k] = b; sa[k] = a; sidx[k] = i;
}

// mask[k][w] bit b (j = w*64+b) set iff j>k, j<n, iou_nms(k,j) >= 0.5.
// Also emits diag (the diagonal 64x64 block of row k) and band (the word
// one to the RIGHT of the diagonal: mask[k][(k>>6)+1]) for the scan.
// Reference does NOT clamp the intersection on the NMS path — replicate
// exactly (contraction off, strict IEEE f32 division, same op order).
__global__ void k_mask(const float* __restrict__ sl, const float* __restrict__ st,
                       const float* __restrict__ sr, const float* __restrict__ sb,
                       const float* __restrict__ sa,
                       u64* __restrict__ mask, u64* __restrict__ diag,
                       u64* __restrict__ band, int n, int wstride) {
  #pragma clang fp contract(off)
  int k = blockIdx.x * blockDim.x + threadIdx.x;
  if (k >= n) return;
  int w = blockIdx.y;
  int jbase = w << 6;
  u64 word = 0;
  if (jbase + 63 > k) {
    float l = sl[k], t = st[k], r = sr[k], b = sb[k], a = sa[k];
    int jend = min(jbase + 64, n);
    for (int j = max(jbase, k + 1); j < jend; ++j) {
      float lmax = fmaxf(l, sl[j]);
      float tmax = fmaxf(t, st[j]);
      float rmin = fminf(r, sr[j]);
      float bmin = fminf(b, sb[j]);
      float wd = rmin - lmax;
      float hd = bmin - tmax;
      float inter = wd * hd;               // no clamp (matches reference NMS path)
      float denom = (a + sa[j]) - inter;
      float q = inter / denom;             // IEEE f32 div
      if (q >= THR) word |= 1ull << (j - jbase);
    }
  }
  mask[(size_t)k * wstride + w] = word;
  int kg = k >> 6;
  if (kg == w) diag[k] = word;
  if (w == kg + 1) band[k] = word;         // superdiagonal word
}

// ---------------------------------------------------------------------------
// Greedy serial NMS scan — 256 threads, fold OFF the critical path:
//  * wave 0: serial chain over diag (LDS); the one word the NEXT chain needs
//    (word g+1) is built from the LDS band via masked shfl-OR-reduce and
//    carried in a REGISTER (bnd) — zero global latency, no rem[] race.
//  * waves 1-3: LAZY fold of group g-1's kept rows into rem[w], w>g only
//    (w==g+1 handled by band; words >= g+2 not read for >= 2 barriers),
//    CONCURRENT with wave 0's chain. 16-deep independent coalesced loads.
//  * ONE barrier per group (round-4: chain and fold serialized by 2).
//  * chain chunk loads unconditional (only compute skipped) so the
//    scheduler pipelines LDS reads across chunks.
// ---------------------------------------------------------------------------
__device__ __forceinline__ void scan_body6(
    const u64* __restrict__ mask, const u64* __restrict__ diag,
    const u64* __restrict__ band, const int* __restrict__ sidx,
    float* __restrict__ keep, int n, int wstride,
    u64* rem, u64* dsh, u64* bsh, int (*kept)[64], int* nk_sh) {
  int t = threadIdx.x, wv = t >> 6, lane = t & 63;
  int ng = (n + 63) >> 6;
  rem[t] = 0;
  if (t < 2) nk_sh[t] = 0;
  int scur = 0;
  u64 bnd = 0;
  if (wv == 0) {
    dsh[lane] = diag[lane];
    bsh[lane] = band[lane];
    if (lane < n) scur = sidx[lane];
  }
  __syncthreads();
  for (int g = 0; g < ng; ++g) {
    int base = g << 6;
    if (wv == 0) {
      // prefetch next group's diag/band/sidx (hides under the chain)
      int nxt = base + 64 + lane;
      u64 dnext = (g + 1 < ng) ? diag[nxt] : 0;
      u64 bnext = (g + 1 < ng) ? band[nxt] : 0;
      int snew = (g + 1 < ng && nxt < n) ? sidx[nxt] : 0;
      u64 s = rem[g] | bnd;                 // bnd = group g-1's word-g bits
      int valid = n - base;
      if (valid < 64) s |= (~0ull) << valid;  // nonexistent boxes = suppressed
      u64 kw = 0;
      #pragma unroll
      for (int c = 0; c < 8; ++c) {
        int b0 = c << 3;
        u64 e0 = dsh[b0 + 0], e1 = dsh[b0 + 1], e2 = dsh[b0 + 2], e3 = dsh[b0 + 3];
        u64 e4 = dsh[b0 + 4], e5 = dsh[b0 + 5], e6 = dsh[b0 + 6], e7 = dsh[b0 + 7];
        if ((unsigned)((s >> b0) & 0xFFull) != 0xFFu) {  // skip compute only
          #define STEP(Q, EQ) if (!((s >> (b0 + Q)) & 1ull)) { kw |= 1ull << (b0 + Q); s |= EQ; }
          STEP(0, e0) STEP(1, e1) STEP(2, e2) STEP(3, e3)
          STEP(4, e4) STEP(5, e5) STEP(6, e6) STEP(7, e7)
          #undef STEP
        }
      }
      if (base + lane < n)
        keep[scur] = ((kw >> lane) & 1ull) ? 1.0f : 0.0f;
      // compact kept bits -> double-buffered LDS list, pad to x16 with 0
      int nk = __popcll(kw);
      if ((kw >> lane) & 1ull) {
        int pos = __popcll(kw & ((1ull << lane) - 1ull));
        kept[g & 1][pos] = lane;
      }
      int npad = (nk + 15) & ~15;
      if (lane >= nk && lane < npad) kept[g & 1][lane] = 0;
      if (lane == 0) nk_sh[g & 1] = nk;
      // band-reduce: group g's kept rows' bits for word g+1 (pure LDS+shfl)
      u64 bv = ((kw >> lane) & 1ull) ? bsh[lane] : 0ull;
      bv |= __shfl_xor(bv, 32);
      bv |= __shfl_xor(bv, 16);
      bv |= __shfl_xor(bv, 8);
      bv |= __shfl_xor(bv, 4);
      bv |= __shfl_xor(bv, 2);
      bv |= __shfl_xor(bv, 1);
      bnd = bv;
      dsh[lane] = dnext;    // after all chain/band reads (wave-ordered LDS)
      bsh[lane] = bnext;
      scur = snew;
    } else {
      // lazy fold: kept rows of group g-1 into rem[w], w > g (w==g+1..)
      int w = t - 64;
      int gp = g - 1;
      if (gp >= 0 && w > g && w < ng) {
        int nkp = nk_sh[gp & 1];
        if (nkp) {
          const int* kp = kept[gp & 1];
          int basep = gp << 6;
          u64 acc = 0;
          for (int i = 0; i < nkp; i += 16) {
            int k0 = kp[i+0],  k1 = kp[i+1],  k2 = kp[i+2],  k3 = kp[i+3];
            int k4 = kp[i+4],  k5 = kp[i+5],  k6 = kp[i+6],  k7 = kp[i+7];
            int k8 = kp[i+8],  k9 = kp[i+9],  k10 = kp[i+10], k11 = kp[i+11];
            int k12 = kp[i+12], k13 = kp[i+13], k14 = kp[i+14], k15 = kp[i+15];
            u64 v0 = mask[(size_t)(basep + k0) * wstride + w];
            u64 v1 = mask[(size_t)(basep + k1) * wstride + w];
            u64 v2 = mask[(size_t)(basep + k2) * wstride + w];
            u64 v3 = mask[(size_t)(basep + k3) * wstride + w];
            u64 v4 = mask[(size_t)(basep + k4) * wstride + w];
            u64 v5 = mask[(size_t)(basep + k5) * wstride + w];
            u64 v6 = mask[(size_t)(basep + k6) * wstride + w];
            u64 v7 = mask[(size_t)(basep + k7) * wstride + w];
            u64 v8 = mask[(size_t)(basep + k8) * wstride + w];
            u64 v9 = mask[(size_t)(basep + k9) * wstride + w];
            u64 v10 = mask[(size_t)(basep + k10) * wstride + w];
            u64 v11 = mask[(size_t)(basep + k11) * wstride + w];
            u64 v12 = mask[(size_t)(basep + k12) * wstride + w];
            u64 v13 = mask[(size_t)(basep + k13) * wstride + w];
            u64 v14 = mask[(size_t)(basep + k14) * wstride + w];
            u64 v15 = mask[(size_t)(basep + k15) * wstride + w];
            acc |= v0;
            if (i + 1 < nkp)  acc |= v1;
            if (i + 2 < nkp)  acc |= v2;
            if (i + 3 < nkp)  acc |= v3;
            if (i + 4 < nkp)  acc |= v4;
            if (i + 5 < nkp)  acc |= v5;
            if (i + 6 < nkp)  acc |= v6;
            if (i + 7 < nkp)  acc |= v7;
            if (i + 8 < nkp)  acc |= v8;
            if (i + 9 < nkp)  acc |= v9;
            if (i + 10 < nkp) acc |= v10;
            if (i + 11 < nkp) acc |= v11;
            if (i + 12 < nkp) acc |= v12;
            if (i + 13 < nkp) acc |= v13;
            if (i + 14 < nkp) acc |= v14;
            if (i + 15 < nkp) acc |= v15;
          }
          rem[w] |= acc;
        }
      }
    }
    __syncthreads();
  }
}

__global__ __launch_bounds__(256, 1) void k_scan2(const u64* __restrict__ mask,
                                                  const u64* __restrict__ diag,
                                                  const u64* __restrict__ band,
                                                  const int* __restrict__ sidx,
                                                  float* __restrict__ keep,
                                                  int n, int wstride) {
  __shared__ u64 rem[256];
  __shared__ u64 dsh[64];
  __shared__ u64 bsh[64];
  __shared__ int kept[2][64];
  __shared__ int nk_sh[2];
  scan_body6(mask, diag, band, sidx, keep, n, wstride, rem, dsh, bsh, kept, nk_sh);
}

// Pairwise IoU, original order, WITH clamp. Loose 2e-2 threshold -> fast rcp.
__device__ __forceinline__ float iou_one(float li, float ti, float ri, float bi, float ai,
                                         float lj, float tj, float rj, float bj, float aj) {
  float lmax = fmaxf(li, lj);
  float tmax = fmaxf(ti, tj);
  float rmin = fminf(ri, rj);
  float bmin = fminf(bi, bj);
  float w = fmaxf(rmin - lmax, 0.0f);
  float h = fmaxf(bmin - tmax, 0.0f);
  float inter = w * h;
  float denom = (ai + aj) - inter;
  return inter * __builtin_amdgcn_rcpf(denom);
}

__device__ __forceinline__ void iou_body(const float4* __restrict__ boxes,
                                         float* __restrict__ out,
                                         int n, int rpb, int bx, int by) {
  int nj4 = (n + 3) >> 2;
  int j4 = bx * 256 + threadIdx.x;
  if (j4 >= nj4) return;
  int j = j4 << 2;
  int jc1 = min(j + 1, n - 1), jc2 = min(j + 2, n - 1), jc3 = min(j + 3, n - 1);
  float l0,t0,r0,b0,a0, l1,t1,r1,b1,a1, l2,t2,r2,b2,a2, l3,t3,r3,b3,a3;
  conv_box(boxes[j],   l0,t0,r0,b0,a0);
  conv_box(boxes[jc1], l1,t1,r1,b1,a1);
  conv_box(boxes[jc2], l2,t2,r2,b2,a2);
  conv_box(boxes[jc3], l3,t3,r3,b3,a3);
  bool full = (j + 3) < n;
  for (int rr = 0; rr < rpb; ++rr) {
    int i = by * rpb + rr;
    if (i >= n) return;
    float li,ti,ri,bi,ai;
    conv_box(boxes[i], li,ti,ri,bi,ai);
    float4 o;
    o.x = iou_one(li,ti,ri,bi,ai, l0,t0,r0,b0,a0);
    o.y = iou_one(li,ti,ri,bi,ai, l1,t1,r1,b1,a1);
    o.z = iou_one(li,ti,ri,bi,ai, l2,t2,r2,b2,a2);
    o.w = iou_one(li,ti,ri,bi,ai, l3,t3,r3,b3,a3);
    size_t row = (size_t)i * n;
    if (full) {
      *reinterpret_cast<float4*>(out + row + j) = o;
    } else {
      out[row + j] = o.x;
      if (j + 1 < n) out[row + j + 1] = o.y;
      if (j + 2 < n) out[row + j + 2] = o.z;
    }
  }
}

__global__ void k_iou(const float4* __restrict__ boxes, float* __restrict__ out,
                      int n, int rpb) {
  iou_body(boxes, out, n, rpb, blockIdx.x, blockIdx.y);
}

// Fused: block 0 runs the NMS scan from d_ws while all other blocks stream
// the 400MB IoU matrix — scan latency hides under the write-bound IoU.
// No hazard: scan reads ws + writes keep (=out+NN); iou writes out[0,NN).
__global__ __launch_bounds__(256) void k_fused(const float4* __restrict__ boxes,
                                               float* __restrict__ out,
                                               const u64* __restrict__ mask,
                                               const u64* __restrict__ diag,
                                               const u64* __restrict__ band,
                                               const int* __restrict__ sidx,
                                               float* __restrict__ keep,
                                               int n, int wstride, int rpb, int gx) {
  __shared__ u64 rem[256];
  __shared__ u64 dsh[64];
  __shared__ u64 bsh[64];
  __shared__ int kept[2][64];
  __shared__ int nk_sh[2];
  if (blockIdx.x == 0) {
    scan_body6(mask, diag, band, sidx, keep, n, wstride, rem, dsh, bsh, kept, nk_sh);
    return;
  }
  int id = blockIdx.x - 1;
  iou_body(boxes, out, n, rpb, id % gx, id / gx);
}

extern "C" void kernel_launch(void* const* d_in, const int* in_sizes, int n_in,
                              void* d_out, int out_size, void* d_ws, size_t ws_size,
                              hipStream_t stream) {
  const float* boxes = (const float*)d_in[0];
  const float* scores = (const float*)d_in[1];
  int n = in_sizes[1];
  float* out = (float*)d_out;
  size_t NN = (size_t)n * (size_t)n;
  float* keep = out + NN;

  int words = (n + 63) >> 6;
  int wstride = (words + 3) & ~3;
  size_t need = (size_t)n * wstride * 8          // mask
              + (size_t)words * 64 * 8 * 2       // diag + band
              + 256                              // align slack
              + (size_t)n * 4 * 7;               // sl,st,sr,sb,sa,sidx,rank
  bool use_ws = (ws_size >= need);

  char* base = use_ws ? (char*)d_ws : (char*)d_out;
  size_t off = 0;
  u64* mask = (u64*)(base + off); off += (size_t)n * wstride * 8;
  u64* diag = (u64*)(base + off); off += (size_t)words * 64 * 8;
  u64* band = (u64*)(base + off); off += (size_t)words * 64 * 8;
  off = (off + 255) & ~(size_t)255;
  float* sl  = (float*)(base + off); off += (size_t)n * 4;
  float* st_ = (float*)(base + off); off += (size_t)n * 4;
  float* sr  = (float*)(base + off); off += (size_t)n * 4;
  float* sb  = (float*)(base + off); off += (size_t)n * 4;
  float* sa  = (float*)(base + off); off += (size_t)n * 4;
  int* sidx  = (int*)(base + off); off += (size_t)n * 4;
  int* rank  = (int*)(base + off); off += (size_t)n * 4;

  int nb = (n + 255) / 256;
  k_zero<<<nb, 256, 0, stream>>>(rank, n);

  int jblocks = 40;
  int jchunk = (n + jblocks - 1) / jblocks;
  k_rank<<<dim3(nb, jblocks), 256, 0, stream>>>(scores, rank, n, jchunk);

  k_scatter<<<nb, 256, 0, stream>>>((const float4*)boxes, rank, sl, st_, sr, sb, sa, sidx, n);

  k_mask<<<dim3(nb, words), 256, 0, stream>>>(sl, st_, sr, sb, sa, mask, diag, band, n, wstride);

  int rpb = 10;
  int nj4 = (n + 3) >> 2;
  int gx = (nj4 + 255) / 256;
  int gy = (n + rpb - 1) / rpb;

  if (use_ws) {
    k_fused<<<gx * gy + 1, 256, 0, stream>>>((const float4*)boxes, out, mask, diag,
                                             band, sidx, keep, n, wstride, rpb, gx);
  } else {
    // scratch lives in front of out: must finish scan before iou overwrites it
    k_scan2<<<1, 256, 0, stream>>>(mask, diag, band, sidx, keep, n, wstride);
    k_iou<<<dim3(gx, gy), 256, 0, stream>>>((const float4*)boxes, out, n, rpb);
  }
}